// Round 1
// baseline (191.545 us; speedup 1.0000x reference)
//
#include <hip/hip_runtime.h>

#define NB 4
#define VD 128
#define NSTEPS 226

// ---------------------------------------------------------------------------
// Setup kernel: per batch, compute ray_mat = R^T @ K_inv (3x3) and source (3)
// in the same f32 operation order as the JAX reference.
// ---------------------------------------------------------------------------
__global__ void drr_setup_kernel(const float* __restrict__ tp, float* __restrict__ ws) {
    int b = threadIdx.x;
    if (b >= NB) return;
    const float* q = tp + b * 6;
    float thx = q[0], thy = q[1], thz = q[2];
    // t = -param[3:]; t.z += ISO
    float t0 = -q[3];
    float t1 = -q[4];
    float t2 = (-q[5]) + 1000.0f;

    float cxx = cosf(thx), sxx = sinf(thx);
    float cyy = cosf(thy), syy = sinf(thy);
    float czz = cosf(thz), szz = sinf(thz);

    // A = Rx @ Ry
    float A00 = cyy;          float A01 = 0.0f; float A02 = syy;
    float A10 = sxx*syy;      float A11 = cxx;  float A12 = (-sxx)*cyy;
    float A20 = cxx*(-syy);   float A21 = sxx;  float A22 = cxx*cyy;

    // R = A @ Rz ; Rz = [cz -sz 0; sz cz 0; 0 0 1]
    float R00 = A00*czz + A01*szz;
    float R01 = A00*(-szz) + A01*czz;
    float R02 = A02;
    float R10 = A10*czz + A11*szz;
    float R11 = A10*(-szz) + A11*czz;
    float R12 = A12;
    float R20 = A20*czz + A21*szz;
    float R21 = A20*(-szz) + A21*czz;
    float R22 = A22;

    // Rt = R^T
    float Rt00 = R00, Rt01 = R10, Rt02 = R20;
    float Rt10 = R01, Rt11 = R11, Rt12 = R21;
    float Rt20 = R02, Rt21 = R12, Rt22 = R22;

    // K_inv computed in double (matches np.linalg.inv of the upper-tri K)
    const double K00 = 1500.0 / 1.5;   // SDD / PIX0 = 1000
    const double K11 = 1500.0 / 1.5;   // SDD / PIX1 = 1000
    const float ki00 = (float)(1.0 / K00);
    const float ki11 = (float)(1.0 / K11);
    const float ki02 = (float)((0.0 - 64.0) / K00);  // -cx / K00
    const float ki12 = (float)((0.0 - 64.0) / K11);  // -cy / K11

    // M = Rt @ Kinv  (f32, reference einsum contraction order over k=0,1,2)
    float M00 = Rt00 * ki00;
    float M01 = Rt01 * ki11;
    float M02 = (Rt00 * ki02 + Rt01 * ki12) + Rt02;
    float M10 = Rt10 * ki00;
    float M11 = Rt11 * ki11;
    float M12 = (Rt10 * ki02 + Rt11 * ki12) + Rt12;
    float M20 = Rt20 * ki00;
    float M21 = Rt21 * ki11;
    float M22 = (Rt20 * ki02 + Rt21 * ki12) + Rt22;

    // source = VOL_OFFSET - Rt @ t
    float s0 = 64.0f - ((Rt00*t0 + Rt01*t1) + Rt02*t2);
    float s1 = 64.0f - ((Rt10*t0 + Rt11*t1) + Rt12*t2);
    float s2 = 64.0f - ((Rt20*t0 + Rt21*t1) + Rt22*t2);

    float* o = ws + b * 16;
    o[0] = M00; o[1] = M01; o[2] = M02;
    o[3] = M10; o[4] = M11; o[5] = M12;
    o[6] = M20; o[7] = M21; o[8] = M22;
    o[9] = s0;  o[10] = s1; o[11] = s2;
}

// ---------------------------------------------------------------------------
// Main kernel: one thread per ray. March NSTEPS samples with trilinear
// interpolation (zero outside volume), early-exit when ts >= tmax.
// ---------------------------------------------------------------------------
__global__ __launch_bounds__(256) void drr_proj_kernel(const float* __restrict__ vol,
                                                       const float* __restrict__ ws,
                                                       float* __restrict__ out) {
    const int gid = blockIdx.x * blockDim.x + threadIdx.x;
    const int b = gid >> 14;        // 16384 rays per batch
    const int p = gid & 16383;
    const int h = p >> 7;           // u index
    const int w = p & 127;          // v index

    const float* wb = ws + b * 16;
    const float M00 = wb[0], M01 = wb[1], M02 = wb[2];
    const float M10 = wb[3], M11 = wb[4], M12 = wb[5];
    const float M20 = wb[6], M21 = wb[7], M22 = wb[8];
    const float sx = wb[9], sy = wb[10], sz = wb[11];

    const float u = (float)h + 0.5f;
    const float v = (float)w + 0.5f;

    float dx = (M00*u + M01*v) + M02;
    float dy = (M10*u + M11*v) + M12;
    float dz = (M20*u + M21*v) + M22;
    const float phys = sqrtf((dx*dx + dy*dy) + dz*dz);
    dx /= phys; dy /= phys; dz /= phys;

    const float sdx = (fabsf(dx) < 1e-8f) ? 1e-8f : dx;
    const float sdy = (fabsf(dy) < 1e-8f) ? 1e-8f : dy;
    const float sdz = (fabsf(dz) < 1e-8f) ? 1e-8f : dz;

    const float t0x = (0.0f - sx) / sdx, t1x = (128.0f - sx) / sdx;
    const float t0y = (0.0f - sy) / sdy, t1y = (128.0f - sy) / sdy;
    const float t0z = (0.0f - sz) / sdz, t1z = (128.0f - sz) / sdz;

    float tmin = fmaxf(fmaxf(fminf(t0x, t1x), fminf(t0y, t1y)), fminf(t0z, t1z));
    tmin = fmaxf(tmin, 0.0f);
    const float tmax = fminf(fminf(fmaxf(t0x, t1x), fmaxf(t0y, t1y)), fmaxf(t0z, t1z));

    const float* volb = vol + (size_t)b * (VD * VD * VD);

    float acc = 0.0f;
    #pragma unroll 1
    for (int k = 0; k < NSTEPS; ++k) {
        const float ts = tmin + ((float)k + 0.5f);
        if (!(ts < tmax)) break;   // mask is monotone in k; remaining terms are 0

        const float px = sx + ts * dx;
        const float py = sy + ts * dy;
        const float pz = sz + ts * dz;

        const float fx = floorf(px), fy = floorf(py), fz = floorf(pz);
        const int ix = (int)fx, iy = (int)fy, iz = (int)fz;
        const float frx = px - fx, fry = py - fy, frz = pz - fz;

        const float wx1 = frx, wx0 = 1.0f - frx;
        const float wy1 = fry, wy0 = 1.0f - fry;
        const float wz1 = frz, wz0 = 1.0f - frz;

        const int ix1 = ix + 1, iy1 = iy + 1, iz1 = iz + 1;
        const bool vx0 = (ix  >= 0) && (ix  < VD);
        const bool vx1 = (ix1 >= 0) && (ix1 < VD);
        const bool vy0 = (iy  >= 0) && (iy  < VD);
        const bool vy1 = (iy1 >= 0) && (iy1 < VD);
        const bool vz0 = (iz  >= 0) && (iz  < VD);
        const bool vz1 = (iz1 >= 0) && (iz1 < VD);

        const int cx0 = min(max(ix,  0), VD - 1), cx1 = min(max(ix1, 0), VD - 1);
        const int cy0 = min(max(iy,  0), VD - 1), cy1 = min(max(iy1, 0), VD - 1);
        const int cz0 = min(max(iz,  0), VD - 1), cz1 = min(max(iz1, 0), VD - 1);

        const int bx0 = cx0 * (VD * VD), bx1 = cx1 * (VD * VD);
        const int by0 = cy0 * VD,        by1 = cy1 * VD;

        // Corner order matches reference loops: dx outer, dy, dz inner
        float smp = 0.0f;
        smp += ((vx0 && vy0 && vz0) ? volb[bx0 + by0 + cz0] : 0.0f) * ((wx0 * wy0) * wz0);
        smp += ((vx0 && vy0 && vz1) ? volb[bx0 + by0 + cz1] : 0.0f) * ((wx0 * wy0) * wz1);
        smp += ((vx0 && vy1 && vz0) ? volb[bx0 + by1 + cz0] : 0.0f) * ((wx0 * wy1) * wz0);
        smp += ((vx0 && vy1 && vz1) ? volb[bx0 + by1 + cz1] : 0.0f) * ((wx0 * wy1) * wz1);
        smp += ((vx1 && vy0 && vz0) ? volb[bx1 + by0 + cz0] : 0.0f) * ((wx1 * wy0) * wz0);
        smp += ((vx1 && vy0 && vz1) ? volb[bx1 + by0 + cz1] : 0.0f) * ((wx1 * wy0) * wz1);
        smp += ((vx1 && vy1 && vz0) ? volb[bx1 + by1 + cz0] : 0.0f) * ((wx1 * wy1) * wz0);
        smp += ((vx1 && vy1 && vz1) ? volb[bx1 + by1 + cz1] : 0.0f) * ((wx1 * wy1) * wz1);

        acc += smp;
    }

    out[gid] = acc / 10.0f;
}

extern "C" void kernel_launch(void* const* d_in, const int* in_sizes, int n_in,
                              void* d_out, int out_size, void* d_ws, size_t ws_size,
                              hipStream_t stream) {
    const float* vol = (const float*)d_in[0];   // (4,1,128,128,128) f32
    const float* tp  = (const float*)d_in[1];   // (4,6) f32
    float* out = (float*)d_out;                 // (4,1,128,128) f32
    float* ws  = (float*)d_ws;                  // 4*16 floats used

    hipLaunchKernelGGL(drr_setup_kernel, dim3(1), dim3(64), 0, stream, tp, ws);

    const int total = NB * VD * VD;             // 65536 rays
    hipLaunchKernelGGL(drr_proj_kernel, dim3(total / 256), dim3(256), 0, stream,
                       vol, ws, out);
}

// Round 2
// 128.711 us; speedup vs baseline: 1.4882x; 1.4882x over previous
//
#include <hip/hip_runtime.h>

#define NB 4
#define VD 128
#define NSTEPS 226
#define LPR 8          // lanes per ray

// ---------------------------------------------------------------------------
// Setup kernel: per batch, compute ray_mat = R^T @ K_inv (3x3) and source (3)
// in the same f32 operation order as the JAX reference.
// ---------------------------------------------------------------------------
__global__ void drr_setup_kernel(const float* __restrict__ tp, float* __restrict__ ws) {
    int b = threadIdx.x;
    if (b >= NB) return;
    const float* q = tp + b * 6;
    float thx = q[0], thy = q[1], thz = q[2];
    float t0 = -q[3];
    float t1 = -q[4];
    float t2 = (-q[5]) + 1000.0f;

    float cxx = cosf(thx), sxx = sinf(thx);
    float cyy = cosf(thy), syy = sinf(thy);
    float czz = cosf(thz), szz = sinf(thz);

    // A = Rx @ Ry
    float A00 = cyy;          float A01 = 0.0f; float A02 = syy;
    float A10 = sxx*syy;      float A11 = cxx;  float A12 = (-sxx)*cyy;
    float A20 = cxx*(-syy);   float A21 = sxx;  float A22 = cxx*cyy;

    // R = A @ Rz
    float R00 = A00*czz + A01*szz;
    float R01 = A00*(-szz) + A01*czz;
    float R02 = A02;
    float R10 = A10*czz + A11*szz;
    float R11 = A10*(-szz) + A11*czz;
    float R12 = A12;
    float R20 = A20*czz + A21*szz;
    float R21 = A20*(-szz) + A21*czz;
    float R22 = A22;

    // Rt = R^T
    float Rt00 = R00, Rt01 = R10, Rt02 = R20;
    float Rt10 = R01, Rt11 = R11, Rt12 = R21;
    float Rt20 = R02, Rt21 = R12, Rt22 = R22;

    const double K00 = 1500.0 / 1.5;
    const double K11 = 1500.0 / 1.5;
    const float ki00 = (float)(1.0 / K00);
    const float ki11 = (float)(1.0 / K11);
    const float ki02 = (float)((0.0 - 64.0) / K00);
    const float ki12 = (float)((0.0 - 64.0) / K11);

    float M00 = Rt00 * ki00;
    float M01 = Rt01 * ki11;
    float M02 = (Rt00 * ki02 + Rt01 * ki12) + Rt02;
    float M10 = Rt10 * ki00;
    float M11 = Rt11 * ki11;
    float M12 = (Rt10 * ki02 + Rt11 * ki12) + Rt12;
    float M20 = Rt20 * ki00;
    float M21 = Rt21 * ki11;
    float M22 = (Rt20 * ki02 + Rt21 * ki12) + Rt22;

    float s0 = 64.0f - ((Rt00*t0 + Rt01*t1) + Rt02*t2);
    float s1 = 64.0f - ((Rt10*t0 + Rt11*t1) + Rt12*t2);
    float s2 = 64.0f - ((Rt20*t0 + Rt21*t1) + Rt22*t2);

    float* o = ws + b * 16;
    o[0] = M00; o[1] = M01; o[2] = M02;
    o[3] = M10; o[4] = M11; o[5] = M12;
    o[6] = M20; o[7] = M21; o[8] = M22;
    o[9] = s0;  o[10] = s1; o[11] = s2;
}

// ---------------------------------------------------------------------------
// Main kernel: LPR lanes per ray; lane j marches steps j, j+LPR, ...
// then an 8-lane shuffle reduction combines partials.
// ---------------------------------------------------------------------------
__global__ __launch_bounds__(256) void drr_proj_kernel(const float* __restrict__ vol,
                                                       const float* __restrict__ ws,
                                                       float* __restrict__ out) {
    const int gtid = blockIdx.x * blockDim.x + threadIdx.x;
    const int ray  = gtid >> 3;       // gtid / LPR
    const int phase = gtid & (LPR - 1);

    const int b = ray >> 14;          // 16384 rays per batch
    const int p = ray & 16383;
    const int h = p >> 7;             // u index
    const int w = p & 127;            // v index

    const float* wb = ws + b * 16;
    const float M00 = wb[0], M01 = wb[1], M02 = wb[2];
    const float M10 = wb[3], M11 = wb[4], M12 = wb[5];
    const float M20 = wb[6], M21 = wb[7], M22 = wb[8];
    const float sx = wb[9], sy = wb[10], sz = wb[11];

    const float u = (float)h + 0.5f;
    const float v = (float)w + 0.5f;

    float dx = (M00*u + M01*v) + M02;
    float dy = (M10*u + M11*v) + M12;
    float dz = (M20*u + M21*v) + M22;
    const float phys = sqrtf((dx*dx + dy*dy) + dz*dz);
    dx /= phys; dy /= phys; dz /= phys;

    const float sdx = (fabsf(dx) < 1e-8f) ? 1e-8f : dx;
    const float sdy = (fabsf(dy) < 1e-8f) ? 1e-8f : dy;
    const float sdz = (fabsf(dz) < 1e-8f) ? 1e-8f : dz;

    const float t0x = (0.0f - sx) / sdx, t1x = (128.0f - sx) / sdx;
    const float t0y = (0.0f - sy) / sdy, t1y = (128.0f - sy) / sdy;
    const float t0z = (0.0f - sz) / sdz, t1z = (128.0f - sz) / sdz;

    float tmin = fmaxf(fmaxf(fminf(t0x, t1x), fminf(t0y, t1y)), fminf(t0z, t1z));
    tmin = fmaxf(tmin, 0.0f);
    const float tmax = fminf(fminf(fmaxf(t0x, t1x), fmaxf(t0y, t1y)), fmaxf(t0z, t1z));

    const float* volb = vol + (size_t)b * (VD * VD * VD);

    float acc = 0.0f;
    #pragma unroll 1
    for (int k = phase; k < NSTEPS; k += LPR) {
        const float ts = tmin + ((float)k + 0.5f);   // same arithmetic as reference
        if (!(ts < tmax)) break;                     // monotone per lane

        const float px = sx + ts * dx;
        const float py = sy + ts * dy;
        const float pz = sz + ts * dz;

        const float fx = floorf(px), fy = floorf(py), fz = floorf(pz);
        const int ix = (int)fx, iy = (int)fy, iz = (int)fz;
        const float frx = px - fx, fry = py - fy, frz = pz - fz;

        const float wx1 = frx, wx0 = 1.0f - frx;
        const float wy1 = fry, wy0 = 1.0f - fry;
        const float wz1 = frz, wz0 = 1.0f - frz;

        const int ix1 = ix + 1, iy1 = iy + 1, iz1 = iz + 1;
        const bool vx0 = (ix  >= 0) && (ix  < VD);
        const bool vx1 = (ix1 >= 0) && (ix1 < VD);
        const bool vy0 = (iy  >= 0) && (iy  < VD);
        const bool vy1 = (iy1 >= 0) && (iy1 < VD);
        const bool vz0 = (iz  >= 0) && (iz  < VD);
        const bool vz1 = (iz1 >= 0) && (iz1 < VD);

        const int cx0 = min(max(ix,  0), VD - 1), cx1 = min(max(ix1, 0), VD - 1);
        const int cy0 = min(max(iy,  0), VD - 1), cy1 = min(max(iy1, 0), VD - 1);
        const int cz0 = min(max(iz,  0), VD - 1), cz1 = min(max(iz1, 0), VD - 1);

        const int bx0 = cx0 * (VD * VD), bx1 = cx1 * (VD * VD);
        const int by0 = cy0 * VD,        by1 = cy1 * VD;

        float smp = 0.0f;
        smp += ((vx0 && vy0 && vz0) ? volb[bx0 + by0 + cz0] : 0.0f) * ((wx0 * wy0) * wz0);
        smp += ((vx0 && vy0 && vz1) ? volb[bx0 + by0 + cz1] : 0.0f) * ((wx0 * wy0) * wz1);
        smp += ((vx0 && vy1 && vz0) ? volb[bx0 + by1 + cz0] : 0.0f) * ((wx0 * wy1) * wz0);
        smp += ((vx0 && vy1 && vz1) ? volb[bx0 + by1 + cz1] : 0.0f) * ((wx0 * wy1) * wz1);
        smp += ((vx1 && vy0 && vz0) ? volb[bx1 + by0 + cz0] : 0.0f) * ((wx1 * wy0) * wz0);
        smp += ((vx1 && vy0 && vz1) ? volb[bx1 + by0 + cz1] : 0.0f) * ((wx1 * wy0) * wz1);
        smp += ((vx1 && vy1 && vz0) ? volb[bx1 + by1 + cz0] : 0.0f) * ((wx1 * wy1) * wz0);
        smp += ((vx1 && vy1 && vz1) ? volb[bx1 + by1 + cz1] : 0.0f) * ((wx1 * wy1) * wz1);

        acc += smp;
    }

    // 8-lane butterfly reduce within the ray's lane group
    acc += __shfl_xor(acc, 1, 64);
    acc += __shfl_xor(acc, 2, 64);
    acc += __shfl_xor(acc, 4, 64);

    if (phase == 0) out[ray] = acc / 10.0f;
}

extern "C" void kernel_launch(void* const* d_in, const int* in_sizes, int n_in,
                              void* d_out, int out_size, void* d_ws, size_t ws_size,
                              hipStream_t stream) {
    const float* vol = (const float*)d_in[0];   // (4,1,128,128,128) f32
    const float* tp  = (const float*)d_in[1];   // (4,6) f32
    float* out = (float*)d_out;                 // (4,1,128,128) f32
    float* ws  = (float*)d_ws;

    hipLaunchKernelGGL(drr_setup_kernel, dim3(1), dim3(64), 0, stream, tp, ws);

    const int total_threads = NB * VD * VD * LPR;   // 524288
    hipLaunchKernelGGL(drr_proj_kernel, dim3(total_threads / 256), dim3(256), 0, stream,
                       vol, ws, out);
}